// Round 5
// baseline (358.434 us; speedup 1.0000x reference)
//
#include <hip/hip_runtime.h>
#include <math.h>

// d: (262144, 256) float32, row-major. s[j] = sum_i d[i][j]^2,
// out = 0.001 * sqrt(sum_j (s[j]-1)^2). Memory-bound: 268 MB stream,
// roofline ~43 us @ 6.3 TB/s.
//
// R3 lesson: nontemporal loads = 8x SLOWER (latency-bound, cache-bypass).
// R4->R5: replaced 524k same-line L2 atomicAdds (serialized tail) with a
// 3-stage tree reduce: colsq -> per-block partials (plain stores),
// reduce2 (2048->64 rows), finalize (64->scalar). No memset needed.

#define NROW   262144
#define NCOL   256
#define NCOLV  64        // columns in float4 units
#define GRID   2048      // 8 blocks/CU on 256 CUs
#define ITERS  (NROW / 4 / GRID)   // 32 four-row groups per block
#define GRID2  64        // stage-2 blocks: each reduces 32 partial rows

// ws layout: [0 .. 2 MB) partial[2048][256], [2 MB .. 2 MB+64KB) partial2[64][256]

__global__ __launch_bounds__(256) void colsq_kernel(
        const float4* __restrict__ d, float* __restrict__ partial) {
    const int tid   = threadIdx.x;
    const int c4    = tid & 63;   // float4 column index 0..63
    const int r_off = tid >> 6;   // row within 4-row group, 0..3

    float4 acc = make_float4(0.f, 0.f, 0.f, 0.f);

    // Each block streams a contiguous 128 KiB chunk; one iter = 4 rows = 4 KiB
    // of wave-contiguous dwordx4 loads. unroll 8 -> 8 loads in flight/thread.
    const size_t base_rg = (size_t)blockIdx.x * ITERS;
#pragma unroll 8
    for (int i = 0; i < ITERS; ++i) {
        const size_t row = (base_rg + i) * 4 + r_off;
        const float4 v = d[row * NCOLV + c4];
        acc.x += v.x * v.x;
        acc.y += v.y * v.y;
        acc.z += v.z * v.z;
        acc.w += v.w * v.w;
    }

    // Block reduce across the 4 r_off groups via LDS (2-way bank alias = free).
    __shared__ float lds[4 * NCOL];
    float4* l4 = (float4*)lds;
    l4[r_off * NCOLV + c4] = acc;          // contiguous b128 per wave
    __syncthreads();
    float s = lds[tid] + lds[NCOL + tid] + lds[2 * NCOL + tid] + lds[3 * NCOL + tid];
    partial[(size_t)blockIdx.x * NCOL + tid] = s;   // coalesced 1 KiB store
}

__global__ __launch_bounds__(256) void reduce2_kernel(
        const float* __restrict__ partial, float* __restrict__ partial2) {
    const int tid = threadIdx.x;
    const int base = blockIdx.x * (GRID / GRID2);   // 32 rows per block
    float s = 0.f;
#pragma unroll 8
    for (int r = 0; r < GRID / GRID2; ++r)
        s += partial[(size_t)(base + r) * NCOL + tid];   // coalesced
    partial2[(size_t)blockIdx.x * NCOL + tid] = s;
}

__global__ __launch_bounds__(256) void finalize_kernel(
        const float* __restrict__ partial2, float* __restrict__ out) {
    const int tid = threadIdx.x;
    float s = 0.f;
#pragma unroll 8
    for (int r = 0; r < GRID2; ++r)
        s += partial2[(size_t)r * NCOL + tid];           // coalesced
    float diff = s - 1.0f;
    float v = diff * diff;
#pragma unroll
    for (int off = 32; off > 0; off >>= 1)
        v += __shfl_down(v, off, 64);
    __shared__ float ws[4];
    if ((tid & 63) == 0) ws[tid >> 6] = v;
    __syncthreads();
    if (tid == 0)
        out[0] = 0.001f * sqrtf(ws[0] + ws[1] + ws[2] + ws[3]);
}

extern "C" void kernel_launch(void* const* d_in, const int* in_sizes, int n_in,
                              void* d_out, int out_size, void* d_ws, size_t ws_size,
                              hipStream_t stream) {
    const float4* d  = (const float4*)d_in[0];
    float* partial   = (float*)d_ws;                          // 2 MB
    float* partial2  = (float*)((char*)d_ws + (size_t)GRID * NCOL * sizeof(float));
    float* out       = (float*)d_out;

    colsq_kernel  <<<GRID,  256, 0, stream>>>(d, partial);
    reduce2_kernel<<<GRID2, 256, 0, stream>>>(partial, partial2);
    finalize_kernel<<<1,    256, 0, stream>>>(partial2, out);
}